// Round 3
// baseline (1073.943 us; speedup 1.0000x reference)
//
#include <hip/hip_runtime.h>
#include <cstdint>
#include <cstddef>

#define NHEAD 4
#define HID 64
#define NCOL 256          // NHEAD*HID
#define INDIM 128
#define PREDDIM 16
#define RELNUM 50
#define NLAYER 3
#define MLP_TILE 16
#define SCAN_CHUNK 1024

#define RPT32(M) M(0)M(1)M(2)M(3)M(4)M(5)M(6)M(7)M(8)M(9)M(10)M(11)M(12)M(13)M(14)M(15)M(16)M(17)M(18)M(19)M(20)M(21)M(22)M(23)M(24)M(25)M(26)M(27)M(28)M(29)M(30)M(31)

// ---------------- node scoring MLP ----------------
// h0[n,k] = sum_j relu(dot(X[n,:],W1[k,j,:]) + b1[k,j]) * W2[k,j] + b2[k]
// Thread = column c = k*64+j; W1 row held in 32 NAMED float4 VGPR variables
// (named, not an array: round-1 showed float w[128] never promoted -> scratch,
// VGPR_Count=76, FETCH 50 GB). Node-tile X loads are block-uniform broadcasts.
__global__ __launch_bounds__(256, 2) void mlp_kernel(
    const float* __restrict__ X, const float* __restrict__ W1,
    const float* __restrict__ b1, const float* __restrict__ W2,
    const float* __restrict__ b2, float* __restrict__ h0, int N)
{
    const int c = threadIdx.x;          // 0..255
    const int k = c >> 6;               // head
    const float4* W4 = reinterpret_cast<const float4*>(W1) + (size_t)c * (INDIM / 4);
#define DECLW(i) float4 wq##i = W4[i];
    RPT32(DECLW)
#undef DECLW
    const float bb = b1[c];
    const float w2s = W2[c];
    const float bk = b2[k];

    for (int n0 = blockIdx.x * MLP_TILE; n0 < N; n0 += gridDim.x * MLP_TILE) {
        const int nmax = min(MLP_TILE, N - n0);
        for (int n = 0; n < nmax; n++) {
            const float4* A4 = reinterpret_cast<const float4*>(X) + (size_t)(n0 + n) * (INDIM / 4);
            float a0 = 0.f, a1 = 0.f, a2 = 0.f, a3 = 0.f;
#define FMA4(i) { float4 av = A4[i]; \
            a0 = fmaf(wq##i.x, av.x, a0); \
            a1 = fmaf(wq##i.y, av.y, a1); \
            a2 = fmaf(wq##i.z, av.z, a2); \
            a3 = fmaf(wq##i.w, av.w, a3); }
            RPT32(FMA4)
#undef FMA4
            float acc = bb + ((a0 + a1) + (a2 + a3));
            float v = fmaxf(acc, 0.f) * w2s;
            // sum over 64 lanes of this wave (= over j for head k)
            #pragma unroll
            for (int off = 32; off >= 1; off >>= 1) v += __shfl_down(v, off);
            if ((c & 63) == 0) h0[(size_t)(n0 + n) * NHEAD + k] = v + bk;
        }
    }
}

// ---------------- attention weight table ----------------
// wtab[l][t][h] = exp(leaky_relu(dot(rel_emb[t,:], W_pred[l,:,h]), 0.2))
__global__ void table_kernel(const float* __restrict__ rel_emb,
                             const float* __restrict__ W_pred,
                             float* __restrict__ wtab)
{
    int idx = blockIdx.x * blockDim.x + threadIdx.x;
    if (idx >= NLAYER * RELNUM * NHEAD) return;
    int h = idx & 3;
    int q = idx >> 2;
    int t = q % RELNUM;
    int l = q / RELNUM;
    float acc = 0.f;
    #pragma unroll
    for (int p = 0; p < PREDDIM; p++)
        acc = fmaf(rel_emb[t * PREDDIM + p], W_pred[l * PREDDIM * NHEAD + p * NHEAD + h], acc);
    float e = (acc >= 0.f) ? acc : 0.2f * acc;
    wtab[idx] = __expf(e); // fast exp; |e| small
}

// ---------------- CSR build ----------------
__global__ void count_kernel(const int* __restrict__ dst, int* __restrict__ deg, int E)
{
    int e = blockIdx.x * blockDim.x + threadIdx.x;
    if (e < E) atomicAdd(&deg[dst[e]], 1);
}

__global__ void blocksum_kernel(const int* __restrict__ deg, int* __restrict__ partials, int N)
{
    __shared__ int lds[256];
    int t = threadIdx.x;
    int base = blockIdx.x * SCAN_CHUNK + t * 4;
    int s = 0;
    #pragma unroll
    for (int e = 0; e < 4; e++) { int i = base + e; if (i < N) s += deg[i]; }
    lds[t] = s; __syncthreads();
    for (int off = 128; off >= 1; off >>= 1) {
        if (t < off) lds[t] += lds[t + off];
        __syncthreads();
    }
    if (t == 0) partials[blockIdx.x] = lds[0];
}

__global__ void scanpart_kernel(int* __restrict__ partials, int NB)
{
    if (blockIdx.x == 0 && threadIdx.x == 0) {
        int run = 0;
        for (int i = 0; i < NB; i++) { int v = partials[i]; partials[i] = run; run += v; }
    }
}

__global__ void scanfinal_kernel(const int* __restrict__ deg, const int* __restrict__ partials,
                                 int* __restrict__ row_start, int* __restrict__ cursor, int N)
{
    __shared__ int lds[256];
    int t = threadIdx.x;
    int base = blockIdx.x * SCAN_CHUNK + t * 4;
    int s = 0;
    #pragma unroll
    for (int e = 0; e < 4; e++) { int i = base + e; if (i < N) s += deg[i]; }
    lds[t] = s; __syncthreads();
    if (t == 0) {
        int run = partials[blockIdx.x];
        for (int i = 0; i < 256; i++) { int v = lds[i]; lds[i] = run; run += v; }
    }
    __syncthreads();
    int off = lds[t];
    #pragma unroll
    for (int e = 0; e < 4; e++) {
        int i = base + e;
        if (i < N) { row_start[i] = off; cursor[i] = off; off += deg[i]; }
    }
}

// pack src (17 bits, N<131072) | type (6 bits, <64) << 17
__global__ void scatter_kernel(const int* __restrict__ src, const int* __restrict__ dst,
                               const int* __restrict__ types, int* __restrict__ cursor,
                               int* __restrict__ sorted, int E)
{
    int e = blockIdx.x * blockDim.x + threadIdx.x;
    if (e < E) {
        int d = dst[e];
        int p = atomicAdd(&cursor[d], 1);
        sorted[p] = src[e] | (types[e] << 17);
    }
}

// ---------------- per-layer aggregation ----------------
// thread = (dst, head). MODE 0: hin is (N,4); MODE 1: hin is (N,); both write
// scalar mean(relu(num/den)). MODE 2: fuse centrality scaling + final leaky.
template <int MODE>
__global__ __launch_bounds__(256) void agg_kernel(
    const int* __restrict__ row_start, const int* __restrict__ deg,
    const int* __restrict__ sorted, const float* __restrict__ wt_l,
    const float* __restrict__ hin, float* __restrict__ hout,
    const float* __restrict__ centrality, const float* __restrict__ gamma,
    const float* __restrict__ beta, int N)
{
    __shared__ float wt[RELNUM * NHEAD];
    for (int i = threadIdx.x; i < RELNUM * NHEAD; i += blockDim.x) wt[i] = wt_l[i];
    __syncthreads();

    int gid = blockIdx.x * blockDim.x + threadIdx.x;
    int d = gid >> 2, h = gid & 3;
    if (d >= N) return;

    int b = row_start[d], n = deg[d];
    float num = 0.f, den = 0.f;
    for (int i = 0; i < n; i++) {
        int pk = sorted[b + i];                 // same addr across the quad
        int s = pk & 0x1FFFF;
        int t = pk >> 17;
        float wv = wt[t * NHEAD + h];
        float hv = (MODE == 0) ? hin[(size_t)s * NHEAD + h] : hin[s];
        num = fmaf(wv, hv, num);
        den += wv;
    }
    float r = (n > 0) ? fmaxf(num / den, 0.f) : 0.f;   // relu(segsum(a*h))
    if (MODE == 2) r = (centrality[d] * gamma[h] + beta[h]) * r;
    // mean over the 4 heads (quad of lanes)
    r += __shfl_xor(r, 1);
    r += __shfl_xor(r, 2);
    r *= 0.25f;
    if (h == 0) {
        if (MODE < 2) hout[d] = r;
        else          hout[d] = (r > 0.f) ? r : 0.01f * r;
    }
}

// ---------------- launch ----------------
extern "C" void kernel_launch(void* const* d_in, const int* in_sizes, int n_in,
                              void* d_out, int out_size, void* d_ws, size_t ws_size,
                              hipStream_t stream)
{
    const float* X          = (const float*)d_in[0];
    const float* centrality = (const float*)d_in[1];
    const float* W1         = (const float*)d_in[2];
    const float* b1         = (const float*)d_in[3];
    const float* W2         = (const float*)d_in[4];
    const float* b2         = (const float*)d_in[5];
    const float* rel_emb    = (const float*)d_in[6];
    const float* W_pred     = (const float*)d_in[7];
    const float* gamma      = (const float*)d_in[8];
    const float* beta       = (const float*)d_in[9];
    const int*   edge_types = (const int*)d_in[10];
    const int*   src        = (const int*)d_in[11];
    const int*   dst        = (const int*)d_in[12];
    float* out = (float*)d_out;

    const int N = in_sizes[1];
    const int E = in_sizes[10];

    char* ws = (char*)d_ws;
    size_t off = 0;
    auto alloc = [&](size_t bytes) -> void* {
        void* p = ws + off;
        off = (off + bytes + 255) & ~(size_t)255;
        return p;
    };
    int*   deg       = (int*)alloc((size_t)N * 4);
    int*   row_start = (int*)alloc((size_t)N * 4);
    int*   cursor    = (int*)alloc((size_t)N * 4);
    int*   partials  = (int*)alloc(4096);
    int*   sorted    = (int*)alloc((size_t)E * 4);
    float* wtab      = (float*)alloc((size_t)NLAYER * RELNUM * NHEAD * 4);
    float* h0        = (float*)alloc((size_t)N * NHEAD * 4);
    float* hs        = (float*)alloc((size_t)N * 4);
    float* hs2       = (float*)alloc((size_t)N * 4);
    (void)ws_size; (void)n_in; (void)out_size;

    (void)hipMemsetAsync(deg, 0, (size_t)N * 4, stream);

    const int eb = (E + 255) / 256;
    const int NB = (N + SCAN_CHUNK - 1) / SCAN_CHUNK;
    count_kernel<<<eb, 256, 0, stream>>>(dst, deg, E);
    blocksum_kernel<<<NB, 256, 0, stream>>>(deg, partials, N);
    scanpart_kernel<<<1, 64, 0, stream>>>(partials, NB);
    scanfinal_kernel<<<NB, 256, 0, stream>>>(deg, partials, row_start, cursor, N);
    scatter_kernel<<<eb, 256, 0, stream>>>(src, dst, edge_types, cursor, sorted, E);

    table_kernel<<<(NLAYER * RELNUM * NHEAD + 255) / 256, 256, 0, stream>>>(rel_emb, W_pred, wtab);
    mlp_kernel<<<512, 256, 0, stream>>>(X, W1, b1, W2, b2, h0, N);

    const int ab = (N * NHEAD + 255) / 256;
    agg_kernel<0><<<ab, 256, 0, stream>>>(row_start, deg, sorted, wtab + 0 * RELNUM * NHEAD,
                                          h0, hs, nullptr, nullptr, nullptr, N);
    agg_kernel<1><<<ab, 256, 0, stream>>>(row_start, deg, sorted, wtab + 1 * RELNUM * NHEAD,
                                          hs, hs2, nullptr, nullptr, nullptr, N);
    agg_kernel<2><<<ab, 256, 0, stream>>>(row_start, deg, sorted, wtab + 2 * RELNUM * NHEAD,
                                          hs2, out, centrality, gamma, beta, N);
}

// Round 4
// 686.356 us; speedup vs baseline: 1.5647x; 1.5647x over previous
//
#include <hip/hip_runtime.h>
#include <cstdint>
#include <cstddef>

#define NHEAD 4
#define HID 64
#define NCOL 256          // NHEAD*HID
#define INDIM 128
#define PREDDIM 16
#define RELNUM 50
#define NLAYER 3
#define SCAN_CHUNK 1024
#define MTILE 32          // nodes per block in the MLP GEMM
#define KC 32             // K chunk

// ---------------- W1 transpose (once): W1T[k][c] = W1[c][k] ----------------
__global__ void transpose_w1(const float* __restrict__ W1, float* __restrict__ W1T)
{
    int k = blockIdx.x;        // 0..127
    int c = threadIdx.x;       // 0..255
    W1T[k * NCOL + c] = W1[c * INDIM + k];
}

// ---------------- node scoring MLP as LDS-tiled GEMM ----------------
// h0[n,head] = sum_j relu(dot(X[n,:],W1[c,:]) + b1[c]) * W2[c] + b2[head],
// c = head*64+j. Block: 32 nodes x 256 cols. Thread: 8 nodes x 4 cols ->
// 32 accumulators (~80 VGPR natural pressure; round-1/3 showed holding all
// 128 W1 weights per thread gets sunk back to memory by the allocator).
__global__ __launch_bounds__(256) void mlp_gemm_kernel(
    const float* __restrict__ X, const float* __restrict__ W1T,
    const float* __restrict__ b1, const float* __restrict__ W2,
    const float* __restrict__ b2, float* __restrict__ h0, int N)
{
    __shared__ float A_t[INDIM * MTILE];   // [k][node], 16 KB
    __shared__ float B_ch[KC * NCOL];      // [kk][c],   32 KB

    const int tid  = threadIdx.x;
    const int lane = tid & 63;
    const int w    = tid >> 6;             // wave 0..3 -> nodes w*8..w*8+7
    const int n0   = blockIdx.x * MTILE;

    // ---- stage X tile transposed: A_t[k][node] ----
    {
        const int node = tid >> 3;         // 0..31
        const int kg   = tid & 7;          // k base = kg*16
        int gn = n0 + node; if (gn > N - 1) gn = N - 1;   // clamp; store-guarded later
        const float4* Xp = reinterpret_cast<const float4*>(X + (size_t)gn * INDIM) + kg * 4;
        float4 x0 = Xp[0], x1 = Xp[1], x2 = Xp[2], x3 = Xp[3];
        float xv[16] = { x0.x,x0.y,x0.z,x0.w, x1.x,x1.y,x1.z,x1.w,
                         x2.x,x2.y,x2.z,x2.w, x3.x,x3.y,x3.z,x3.w };
        #pragma unroll
        for (int j = 0; j < 16; j++)
            A_t[(kg * 16 + j) * MTILE + node] = xv[j];
    }

    float acc[8][4];
    #pragma unroll
    for (int i = 0; i < 8; i++)
        #pragma unroll
        for (int j = 0; j < 4; j++) acc[i][j] = 0.f;

    const float4* W1T4 = reinterpret_cast<const float4*>(W1T);
    float4* B4 = reinterpret_cast<float4*>(B_ch);

    for (int c4 = 0; c4 < INDIM / KC; c4++) {
        __syncthreads();                   // prev chunk consumed (also covers A_t writes)
        #pragma unroll
        for (int r = 0; r < 8; r++) {      // 2048 float4 = 256 thr x 8
            int f4 = r * 256 + tid;
            B4[f4] = W1T4[c4 * (KC * NCOL / 4) + f4];
        }
        __syncthreads();

        #pragma unroll
        for (int kk = 0; kk < KC; kk++) {
            float4 bv = B4[kk * (NCOL / 4) + lane];                 // cols 4*lane..+3
            const float* Ap = &A_t[(c4 * KC + kk) * MTILE + w * 8]; // wave-uniform
            float4 a0 = *reinterpret_cast<const float4*>(Ap);
            float4 a1 = *reinterpret_cast<const float4*>(Ap + 4);
            float av[8] = { a0.x,a0.y,a0.z,a0.w, a1.x,a1.y,a1.z,a1.w };
            #pragma unroll
            for (int i = 0; i < 8; i++) {
                acc[i][0] = fmaf(av[i], bv.x, acc[i][0]);
                acc[i][1] = fmaf(av[i], bv.y, acc[i][1]);
                acc[i][2] = fmaf(av[i], bv.z, acc[i][2]);
                acc[i][3] = fmaf(av[i], bv.w, acc[i][3]);
            }
        }
    }

    // ---- epilogue: bias + relu + W2, reduce 16 lanes (64 cols of one head) ----
    const int head  = lane >> 4;
    const int cbase = 4 * lane;
    float b1v0 = b1[cbase], b1v1 = b1[cbase+1], b1v2 = b1[cbase+2], b1v3 = b1[cbase+3];
    float w2v0 = W2[cbase], w2v1 = W2[cbase+1], w2v2 = W2[cbase+2], w2v3 = W2[cbase+3];
    const float bk = b2[head];
    #pragma unroll
    for (int i = 0; i < 8; i++) {
        float s = fmaxf(acc[i][0] + b1v0, 0.f) * w2v0
                + fmaxf(acc[i][1] + b1v1, 0.f) * w2v1
                + fmaxf(acc[i][2] + b1v2, 0.f) * w2v2
                + fmaxf(acc[i][3] + b1v3, 0.f) * w2v3;
        s += __shfl_down(s, 8, 16);
        s += __shfl_down(s, 4, 16);
        s += __shfl_down(s, 2, 16);
        s += __shfl_down(s, 1, 16);
        int gn = n0 + w * 8 + i;
        if ((lane & 15) == 0 && gn < N)
            h0[(size_t)gn * NHEAD + head] = s + bk;
    }
}

// ---------------- attention weight table ----------------
__global__ void table_kernel(const float* __restrict__ rel_emb,
                             const float* __restrict__ W_pred,
                             float* __restrict__ wtab)
{
    int idx = blockIdx.x * blockDim.x + threadIdx.x;
    if (idx >= NLAYER * RELNUM * NHEAD) return;
    int h = idx & 3;
    int q = idx >> 2;
    int t = q % RELNUM;
    int l = q / RELNUM;
    float acc = 0.f;
    #pragma unroll
    for (int p = 0; p < PREDDIM; p++)
        acc = fmaf(rel_emb[t * PREDDIM + p], W_pred[l * PREDDIM * NHEAD + p * NHEAD + h], acc);
    float e = (acc >= 0.f) ? acc : 0.2f * acc;
    wtab[idx] = __expf(e); // fast exp; |e| small
}

// ---------------- CSR build ----------------
__global__ void count_kernel(const int* __restrict__ dst, int* __restrict__ deg, int E)
{
    int e = blockIdx.x * blockDim.x + threadIdx.x;
    if (e < E) atomicAdd(&deg[dst[e]], 1);
}

__global__ void blocksum_kernel(const int* __restrict__ deg, int* __restrict__ partials, int N)
{
    __shared__ int lds[256];
    int t = threadIdx.x;
    int base = blockIdx.x * SCAN_CHUNK + t * 4;
    int s = 0;
    #pragma unroll
    for (int e = 0; e < 4; e++) { int i = base + e; if (i < N) s += deg[i]; }
    lds[t] = s; __syncthreads();
    for (int off = 128; off >= 1; off >>= 1) {
        if (t < off) lds[t] += lds[t + off];
        __syncthreads();
    }
    if (t == 0) partials[blockIdx.x] = lds[0];
}

__global__ void scanpart_kernel(int* __restrict__ partials, int NB)
{
    if (blockIdx.x == 0 && threadIdx.x == 0) {
        int run = 0;
        for (int i = 0; i < NB; i++) { int v = partials[i]; partials[i] = run; run += v; }
    }
}

__global__ void scanfinal_kernel(const int* __restrict__ deg, const int* __restrict__ partials,
                                 int* __restrict__ row_start, int* __restrict__ cursor, int N)
{
    __shared__ int lds[256];
    int t = threadIdx.x;
    int base = blockIdx.x * SCAN_CHUNK + t * 4;
    int s = 0;
    #pragma unroll
    for (int e = 0; e < 4; e++) { int i = base + e; if (i < N) s += deg[i]; }
    lds[t] = s; __syncthreads();
    if (t == 0) {
        int run = partials[blockIdx.x];
        for (int i = 0; i < 256; i++) { int v = lds[i]; lds[i] = run; run += v; }
    }
    __syncthreads();
    int off = lds[t];
    #pragma unroll
    for (int e = 0; e < 4; e++) {
        int i = base + e;
        if (i < N) { row_start[i] = off; cursor[i] = off; off += deg[i]; }
    }
}

// pack src (17 bits, N<131072) | type (6 bits, <64) << 17
__global__ void scatter_kernel(const int* __restrict__ src, const int* __restrict__ dst,
                               const int* __restrict__ types, int* __restrict__ cursor,
                               int* __restrict__ sorted, int E)
{
    int e = blockIdx.x * blockDim.x + threadIdx.x;
    if (e < E) {
        int d = dst[e];
        int p = atomicAdd(&cursor[d], 1);
        sorted[p] = src[e] | (types[e] << 17);
    }
}

// ---------------- per-layer aggregation ----------------
template <int MODE>
__global__ __launch_bounds__(256) void agg_kernel(
    const int* __restrict__ row_start, const int* __restrict__ deg,
    const int* __restrict__ sorted, const float* __restrict__ wt_l,
    const float* __restrict__ hin, float* __restrict__ hout,
    const float* __restrict__ centrality, const float* __restrict__ gamma,
    const float* __restrict__ beta, int N)
{
    __shared__ float wt[RELNUM * NHEAD];
    for (int i = threadIdx.x; i < RELNUM * NHEAD; i += blockDim.x) wt[i] = wt_l[i];
    __syncthreads();

    int gid = blockIdx.x * blockDim.x + threadIdx.x;
    int d = gid >> 2, h = gid & 3;
    if (d >= N) return;

    int b = row_start[d], n = deg[d];
    float num = 0.f, den = 0.f;
    for (int i = 0; i < n; i++) {
        int pk = sorted[b + i];                 // same addr across the quad
        int s = pk & 0x1FFFF;
        int t = pk >> 17;
        float wv = wt[t * NHEAD + h];
        float hv = (MODE == 0) ? hin[(size_t)s * NHEAD + h] : hin[s];
        num = fmaf(wv, hv, num);
        den += wv;
    }
    float r = (n > 0) ? fmaxf(num / den, 0.f) : 0.f;   // relu(segsum(a*h))
    if (MODE == 2) r = (centrality[d] * gamma[h] + beta[h]) * r;
    // mean over the 4 heads (quad of lanes)
    r += __shfl_xor(r, 1);
    r += __shfl_xor(r, 2);
    r *= 0.25f;
    if (h == 0) {
        if (MODE < 2) hout[d] = r;
        else          hout[d] = (r > 0.f) ? r : 0.01f * r;
    }
}

// ---------------- launch ----------------
extern "C" void kernel_launch(void* const* d_in, const int* in_sizes, int n_in,
                              void* d_out, int out_size, void* d_ws, size_t ws_size,
                              hipStream_t stream)
{
    const float* X          = (const float*)d_in[0];
    const float* centrality = (const float*)d_in[1];
    const float* W1         = (const float*)d_in[2];
    const float* b1         = (const float*)d_in[3];
    const float* W2         = (const float*)d_in[4];
    const float* b2         = (const float*)d_in[5];
    const float* rel_emb    = (const float*)d_in[6];
    const float* W_pred     = (const float*)d_in[7];
    const float* gamma      = (const float*)d_in[8];
    const float* beta       = (const float*)d_in[9];
    const int*   edge_types = (const int*)d_in[10];
    const int*   src        = (const int*)d_in[11];
    const int*   dst        = (const int*)d_in[12];
    float* out = (float*)d_out;

    const int N = in_sizes[1];
    const int E = in_sizes[10];

    char* ws = (char*)d_ws;
    size_t off = 0;
    auto alloc = [&](size_t bytes) -> void* {
        void* p = ws + off;
        off = (off + bytes + 255) & ~(size_t)255;
        return p;
    };
    int*   deg       = (int*)alloc((size_t)N * 4);
    int*   row_start = (int*)alloc((size_t)N * 4);
    int*   cursor    = (int*)alloc((size_t)N * 4);
    int*   partials  = (int*)alloc(4096);
    int*   sorted    = (int*)alloc((size_t)E * 4);
    float* wtab      = (float*)alloc((size_t)NLAYER * RELNUM * NHEAD * 4);
    float* h0        = (float*)alloc((size_t)N * NHEAD * 4);
    float* hs        = (float*)alloc((size_t)N * 4);
    float* hs2       = (float*)alloc((size_t)N * 4);
    float* W1T       = (float*)alloc((size_t)INDIM * NCOL * 4);
    (void)ws_size; (void)n_in; (void)out_size;

    (void)hipMemsetAsync(deg, 0, (size_t)N * 4, stream);

    const int eb = (E + 255) / 256;
    const int NB = (N + SCAN_CHUNK - 1) / SCAN_CHUNK;
    count_kernel<<<eb, 256, 0, stream>>>(dst, deg, E);
    blocksum_kernel<<<NB, 256, 0, stream>>>(deg, partials, N);
    scanpart_kernel<<<1, 64, 0, stream>>>(partials, NB);
    scanfinal_kernel<<<NB, 256, 0, stream>>>(deg, partials, row_start, cursor, N);
    scatter_kernel<<<eb, 256, 0, stream>>>(src, dst, edge_types, cursor, sorted, E);

    table_kernel<<<(NLAYER * RELNUM * NHEAD + 255) / 256, 256, 0, stream>>>(rel_emb, W_pred, wtab);
    transpose_w1<<<INDIM, NCOL, 0, stream>>>(W1, W1T);
    mlp_gemm_kernel<<<(N + MTILE - 1) / MTILE, 256, 0, stream>>>(X, W1T, b1, W2, b2, h0, N);

    const int ab = (N * NHEAD + 255) / 256;
    agg_kernel<0><<<ab, 256, 0, stream>>>(row_start, deg, sorted, wtab + 0 * RELNUM * NHEAD,
                                          h0, hs, nullptr, nullptr, nullptr, N);
    agg_kernel<1><<<ab, 256, 0, stream>>>(row_start, deg, sorted, wtab + 1 * RELNUM * NHEAD,
                                          hs, hs2, nullptr, nullptr, nullptr, N);
    agg_kernel<2><<<ab, 256, 0, stream>>>(row_start, deg, sorted, wtab + 2 * RELNUM * NHEAD,
                                          hs2, out, centrality, gamma, beta, N);
}

// Round 5
// 388.612 us; speedup vs baseline: 2.7635x; 1.7662x over previous
//
#include <hip/hip_runtime.h>
#include <cstdint>
#include <cstddef>

#define NHEAD 4
#define HID 64
#define NCOL 256          // NHEAD*HID
#define INDIM 128
#define PREDDIM 16
#define RELNUM 50
#define NLAYER 3
#define MTILE 32          // nodes per block in the MLP GEMM
#define KC 32             // K chunk
#define ECHUNK 8192       // edges per block in bucket build
#define DSHIFT 7          // 128 dsts per bucket
#define DPB 128           // dsts per bucket
#define MAXBUCK 1024      // >= ceil(N/DPB); LDS hist size

// ---------------- W1 transpose (once): W1T[k][c] = W1[c][k] ----------------
__global__ void transpose_w1(const float* __restrict__ W1, float* __restrict__ W1T)
{
    int k = blockIdx.x;        // 0..127
    int c = threadIdx.x;       // 0..255
    W1T[k * NCOL + c] = W1[c * INDIM + k];
}

// ---------------- node scoring MLP as LDS-tiled GEMM ----------------
__global__ __launch_bounds__(256) void mlp_gemm_kernel(
    const float* __restrict__ X, const float* __restrict__ W1T,
    const float* __restrict__ b1, const float* __restrict__ W2,
    const float* __restrict__ b2, float* __restrict__ h0, int N)
{
    __shared__ float A_t[INDIM * MTILE];   // [k][node], 16 KB
    __shared__ float B_ch[KC * NCOL];      // [kk][c],   32 KB

    const int tid  = threadIdx.x;
    const int lane = tid & 63;
    const int w    = tid >> 6;             // wave 0..3 -> nodes w*8..w*8+7
    const int n0   = blockIdx.x * MTILE;

    {
        const int node = tid >> 3;         // 0..31
        const int kg   = tid & 7;          // k base = kg*16
        int gn = n0 + node; if (gn > N - 1) gn = N - 1;   // clamp; store-guarded later
        const float4* Xp = reinterpret_cast<const float4*>(X + (size_t)gn * INDIM) + kg * 4;
        float4 x0 = Xp[0], x1 = Xp[1], x2 = Xp[2], x3 = Xp[3];
        float xv[16] = { x0.x,x0.y,x0.z,x0.w, x1.x,x1.y,x1.z,x1.w,
                         x2.x,x2.y,x2.z,x2.w, x3.x,x3.y,x3.z,x3.w };
        #pragma unroll
        for (int j = 0; j < 16; j++)
            A_t[(kg * 16 + j) * MTILE + node] = xv[j];
    }

    float acc[8][4];
    #pragma unroll
    for (int i = 0; i < 8; i++)
        #pragma unroll
        for (int j = 0; j < 4; j++) acc[i][j] = 0.f;

    const float4* W1T4 = reinterpret_cast<const float4*>(W1T);
    float4* B4 = reinterpret_cast<float4*>(B_ch);

    for (int c4 = 0; c4 < INDIM / KC; c4++) {
        __syncthreads();
        #pragma unroll
        for (int r = 0; r < 8; r++) {
            int f4 = r * 256 + tid;
            B4[f4] = W1T4[c4 * (KC * NCOL / 4) + f4];
        }
        __syncthreads();

        #pragma unroll
        for (int kk = 0; kk < KC; kk++) {
            float4 bv = B4[kk * (NCOL / 4) + lane];
            const float* Ap = &A_t[(c4 * KC + kk) * MTILE + w * 8];
            float4 a0 = *reinterpret_cast<const float4*>(Ap);
            float4 a1 = *reinterpret_cast<const float4*>(Ap + 4);
            float av[8] = { a0.x,a0.y,a0.z,a0.w, a1.x,a1.y,a1.z,a1.w };
            #pragma unroll
            for (int i = 0; i < 8; i++) {
                acc[i][0] = fmaf(av[i], bv.x, acc[i][0]);
                acc[i][1] = fmaf(av[i], bv.y, acc[i][1]);
                acc[i][2] = fmaf(av[i], bv.z, acc[i][2]);
                acc[i][3] = fmaf(av[i], bv.w, acc[i][3]);
            }
        }
    }

    const int head  = lane >> 4;
    const int cbase = 4 * lane;
    float b1v0 = b1[cbase], b1v1 = b1[cbase+1], b1v2 = b1[cbase+2], b1v3 = b1[cbase+3];
    float w2v0 = W2[cbase], w2v1 = W2[cbase+1], w2v2 = W2[cbase+2], w2v3 = W2[cbase+3];
    const float bk = b2[head];
    #pragma unroll
    for (int i = 0; i < 8; i++) {
        float s = fmaxf(acc[i][0] + b1v0, 0.f) * w2v0
                + fmaxf(acc[i][1] + b1v1, 0.f) * w2v1
                + fmaxf(acc[i][2] + b1v2, 0.f) * w2v2
                + fmaxf(acc[i][3] + b1v3, 0.f) * w2v3;
        s += __shfl_down(s, 8, 16);
        s += __shfl_down(s, 4, 16);
        s += __shfl_down(s, 2, 16);
        s += __shfl_down(s, 1, 16);
        int gn = n0 + w * 8 + i;
        if ((lane & 15) == 0 && gn < N)
            h0[(size_t)gn * NHEAD + head] = s + bk;
    }
}

// ---------------- attention weight table ----------------
__global__ void table_kernel(const float* __restrict__ rel_emb,
                             const float* __restrict__ W_pred,
                             float* __restrict__ wtab)
{
    int idx = blockIdx.x * blockDim.x + threadIdx.x;
    if (idx >= NLAYER * RELNUM * NHEAD) return;
    int h = idx & 3;
    int q = idx >> 2;
    int t = q % RELNUM;
    int l = q / RELNUM;
    float acc = 0.f;
    #pragma unroll
    for (int p = 0; p < PREDDIM; p++)
        acc = fmaf(rel_emb[t * PREDDIM + p], W_pred[l * PREDDIM * NHEAD + p * NHEAD + h], acc);
    float e = (acc >= 0.f) ? acc : 0.2f * acc;
    wtab[idx] = __expf(e);
}

// ---------------- bucketed CSR build ----------------
// Round-4 scatter wrote 194 MB HBM (one line writeback per 4B store, random
// across XCDs). Bin edges into dst-range buckets so final CSR writes for a
// dst range come from ONE block (-> one XCD L2, full write combining).

// A1: per-block LDS histogram -> global bucket sizes (few atomics)
__global__ __launch_bounds__(256) void bucket_count_kernel(
    const int* __restrict__ dst, int* __restrict__ bucket_size, int E, int nbuck)
{
    __shared__ int hist[MAXBUCK];
    const int tid = threadIdx.x;
    #pragma unroll
    for (int r = 0; r < MAXBUCK / 256; r++) hist[r * 256 + tid] = 0;
    __syncthreads();
    const int base = blockIdx.x * ECHUNK;
    const int end  = min(base + ECHUNK, E);
    for (int i = base + tid; i < end; i += 256)
        atomicAdd(&hist[dst[i] >> DSHIFT], 1);
    __syncthreads();
    for (int b = tid; b < nbuck; b += 256)
        if (hist[b]) atomicAdd(&bucket_size[b], hist[b]);
}

// exclusive scan of bucket sizes (nbuck <= 1024), one block
__global__ __launch_bounds__(1024) void scan_buckets_kernel(
    const int* __restrict__ bucket_size, int* __restrict__ bucket_start,
    int* __restrict__ bucket_cursor, int nbuck)
{
    __shared__ int s[1024];
    const int t = threadIdx.x;
    int v = (t < nbuck) ? bucket_size[t] : 0;
    s[t] = v;
    __syncthreads();
    for (int off = 1; off < 1024; off <<= 1) {
        int u = (t >= off) ? s[t - off] : 0;
        __syncthreads();
        s[t] += u;
        __syncthreads();
    }
    if (t < nbuck) {
        int ex = s[t] - v;
        bucket_start[t]  = ex;
        bucket_cursor[t] = ex;
    }
}

// A2: bin edges into bucket regions, packed src|type<<17|dstLow<<23
__global__ __launch_bounds__(256) void bucket_scatter_kernel(
    const int* __restrict__ src, const int* __restrict__ dst,
    const int* __restrict__ types, int* __restrict__ bucket_cursor,
    int* __restrict__ bucketed, int E, int nbuck)
{
    __shared__ int hist[MAXBUCK];   // then per-bucket base
    __shared__ int cur[MAXBUCK];
    const int tid = threadIdx.x;
    #pragma unroll
    for (int r = 0; r < MAXBUCK / 256; r++) {
        hist[r * 256 + tid] = 0;
        cur[r * 256 + tid] = 0;
    }
    __syncthreads();
    const int base = blockIdx.x * ECHUNK;
    const int end  = min(base + ECHUNK, E);
    for (int i = base + tid; i < end; i += 256)
        atomicAdd(&hist[dst[i] >> DSHIFT], 1);
    __syncthreads();
    for (int b = tid; b < nbuck; b += 256) {
        int c = hist[b];
        if (c) hist[b] = atomicAdd(&bucket_cursor[b], c);   // reserve block's range
    }
    __syncthreads();
    for (int i = base + tid; i < end; i += 256) {
        int d = dst[i];
        int b = d >> DSHIFT;
        int r = atomicAdd(&cur[b], 1);
        bucketed[hist[b] + r] = src[i] | (types[i] << 17) | ((d & (DPB - 1)) << 23);
    }
}

// B: one block per bucket. LDS hist over 128 local dsts -> scan -> write
// row_start/deg and final sorted[] (output region owned by this block).
__global__ __launch_bounds__(256) void bucket_to_csr_kernel(
    const int* __restrict__ bucket_start, const int* __restrict__ bucket_size,
    const int* __restrict__ bucketed, int* __restrict__ sorted,
    int* __restrict__ row_start, int* __restrict__ deg, int N)
{
    __shared__ int cnt[DPB];
    __shared__ int sc[DPB];
    __shared__ int rs[DPB];
    __shared__ int cur[DPB];
    const int tid = threadIdx.x;
    const int b   = blockIdx.x;
    const int d0  = b << DSHIFT;
    const int nd  = min(DPB, N - d0);
    const int s0  = bucket_start[b];
    const int ne  = bucket_size[b];

    if (tid < DPB) { cnt[tid] = 0; cur[tid] = 0; }
    __syncthreads();
    for (int i = tid; i < ne; i += 256)
        atomicAdd(&cnt[(bucketed[s0 + i] >> 23) & (DPB - 1)], 1);
    __syncthreads();
    // exclusive scan over 128 (Hillis-Steele, inclusive then subtract)
    int v = (tid < DPB) ? cnt[tid] : 0;
    if (tid < DPB) sc[tid] = v;
    __syncthreads();
    for (int off = 1; off < DPB; off <<= 1) {
        int u = (tid < DPB && tid >= off) ? sc[tid - off] : 0;
        __syncthreads();
        if (tid < DPB) sc[tid] += u;
        __syncthreads();
    }
    if (tid < DPB) {
        int ex = sc[tid] - v;
        rs[tid] = s0 + ex;
        if (tid < nd) {
            row_start[d0 + tid] = s0 + ex;
            deg[d0 + tid] = v;
        }
    }
    __syncthreads();
    for (int i = tid; i < ne; i += 256) {
        int pk = bucketed[s0 + i];
        int d  = (pk >> 23) & (DPB - 1);
        int r  = atomicAdd(&cur[d], 1);
        sorted[rs[d] + r] = pk & 0x7FFFFF;   // src | type<<17
    }
}

// ---------------- per-layer aggregation ----------------
template <int MODE>
__global__ __launch_bounds__(256) void agg_kernel(
    const int* __restrict__ row_start, const int* __restrict__ deg,
    const int* __restrict__ sorted, const float* __restrict__ wt_l,
    const float* __restrict__ hin, float* __restrict__ hout,
    const float* __restrict__ centrality, const float* __restrict__ gamma,
    const float* __restrict__ beta, int N)
{
    __shared__ float wt[RELNUM * NHEAD];
    for (int i = threadIdx.x; i < RELNUM * NHEAD; i += blockDim.x) wt[i] = wt_l[i];
    __syncthreads();

    int gid = blockIdx.x * blockDim.x + threadIdx.x;
    int d = gid >> 2, h = gid & 3;
    if (d >= N) return;

    int b = row_start[d], n = deg[d];
    float num = 0.f, den = 0.f;
    for (int i = 0; i < n; i++) {
        int pk = sorted[b + i];                 // same addr across the quad
        int s = pk & 0x1FFFF;
        int t = pk >> 17;
        float wv = wt[t * NHEAD + h];
        float hv = (MODE == 0) ? hin[(size_t)s * NHEAD + h] : hin[s];
        num = fmaf(wv, hv, num);
        den += wv;
    }
    float r = (n > 0) ? fmaxf(num / den, 0.f) : 0.f;   // relu(segsum(a*h))
    if (MODE == 2) r = (centrality[d] * gamma[h] + beta[h]) * r;
    r += __shfl_xor(r, 1);
    r += __shfl_xor(r, 2);
    r *= 0.25f;
    if (h == 0) {
        if (MODE < 2) hout[d] = r;
        else          hout[d] = (r > 0.f) ? r : 0.01f * r;
    }
}

// ---------------- launch ----------------
extern "C" void kernel_launch(void* const* d_in, const int* in_sizes, int n_in,
                              void* d_out, int out_size, void* d_ws, size_t ws_size,
                              hipStream_t stream)
{
    const float* X          = (const float*)d_in[0];
    const float* centrality = (const float*)d_in[1];
    const float* W1         = (const float*)d_in[2];
    const float* b1         = (const float*)d_in[3];
    const float* W2         = (const float*)d_in[4];
    const float* b2         = (const float*)d_in[5];
    const float* rel_emb    = (const float*)d_in[6];
    const float* W_pred     = (const float*)d_in[7];
    const float* gamma      = (const float*)d_in[8];
    const float* beta       = (const float*)d_in[9];
    const int*   edge_types = (const int*)d_in[10];
    const int*   src        = (const int*)d_in[11];
    const int*   dst        = (const int*)d_in[12];
    float* out = (float*)d_out;

    const int N = in_sizes[1];
    const int E = in_sizes[10];
    const int nbuck = (N + DPB - 1) / DPB;

    char* ws = (char*)d_ws;
    size_t off = 0;
    auto alloc = [&](size_t bytes) -> void* {
        void* p = ws + off;
        off = (off + bytes + 255) & ~(size_t)255;
        return p;
    };
    int*   deg       = (int*)alloc((size_t)N * 4);
    int*   row_start = (int*)alloc((size_t)N * 4);
    int*   bsize     = (int*)alloc((size_t)MAXBUCK * 4);
    int*   bstart    = (int*)alloc((size_t)MAXBUCK * 4);
    int*   bcursor   = (int*)alloc((size_t)MAXBUCK * 4);
    int*   bucketed  = (int*)alloc((size_t)E * 4);
    int*   sorted    = (int*)alloc((size_t)E * 4);
    float* wtab      = (float*)alloc((size_t)NLAYER * RELNUM * NHEAD * 4);
    float* h0        = (float*)alloc((size_t)N * NHEAD * 4);
    float* hs        = (float*)alloc((size_t)N * 4);
    float* hs2       = (float*)alloc((size_t)N * 4);
    float* W1T       = (float*)alloc((size_t)INDIM * NCOL * 4);
    (void)ws_size; (void)n_in; (void)out_size;

    (void)hipMemsetAsync(bsize, 0, (size_t)MAXBUCK * 4, stream);

    const int eb = (E + ECHUNK - 1) / ECHUNK;
    bucket_count_kernel<<<eb, 256, 0, stream>>>(dst, bsize, E, nbuck);
    scan_buckets_kernel<<<1, 1024, 0, stream>>>(bsize, bstart, bcursor, nbuck);
    bucket_scatter_kernel<<<eb, 256, 0, stream>>>(src, dst, edge_types, bcursor,
                                                  bucketed, E, nbuck);
    bucket_to_csr_kernel<<<nbuck, 256, 0, stream>>>(bstart, bsize, bucketed, sorted,
                                                    row_start, deg, N);

    table_kernel<<<(NLAYER * RELNUM * NHEAD + 255) / 256, 256, 0, stream>>>(rel_emb, W_pred, wtab);
    transpose_w1<<<INDIM, NCOL, 0, stream>>>(W1, W1T);
    mlp_gemm_kernel<<<(N + MTILE - 1) / MTILE, 256, 0, stream>>>(X, W1T, b1, W2, b2, h0, N);

    const int ab = (N * NHEAD + 255) / 256;
    agg_kernel<0><<<ab, 256, 0, stream>>>(row_start, deg, sorted, wtab + 0 * RELNUM * NHEAD,
                                          h0, hs, nullptr, nullptr, nullptr, N);
    agg_kernel<1><<<ab, 256, 0, stream>>>(row_start, deg, sorted, wtab + 1 * RELNUM * NHEAD,
                                          hs, hs2, nullptr, nullptr, nullptr, N);
    agg_kernel<2><<<ab, 256, 0, stream>>>(row_start, deg, sorted, wtab + 2 * RELNUM * NHEAD,
                                          hs2, out, centrality, gamma, beta, N);
}